// Round 4
// baseline (304.549 us; speedup 1.0000x reference)
//
#include <hip/hip_runtime.h>
#include <hip/hip_bf16.h>

// DialogueGCN on MI355X — fp32 in/out; bf16 MFMA for the GEMMs, fp32 for the
// banded softmax (precision-critical). Off-band attn entries are <= e^-64
// (row max >= ||x_i||^2 ~ chi^2_128) -> dropped entirely; only the 21-wide
// band matters. Softmax Z still counts the (N-band) off-band zeros.

#define NN   6144
#define DD   128
#define WINW 10

typedef unsigned short u16;
typedef __attribute__((ext_vector_type(8))) short bf16x8;  // MFMA A/B frag (4 VGPR)
typedef __attribute__((ext_vector_type(4))) float f32x4;   // MFMA C/D frag

__device__ __forceinline__ float b2f(u16 u) {
    return __uint_as_float(((unsigned int)u) << 16);
}
__device__ __forceinline__ u16 f2b(float f) {
    __hip_bfloat16 h = __float2bfloat16(f);   // RNE
    return *reinterpret_cast<u16*>(&h);
}

// ---------------- prep: blocks [0,64) pack bf16 B^T weights; [64,160) attn --
// W1T/W2T: [640][128] bf16, W1T[n][k] = W_sel(n)[k][n&127]  (B pre-transposed
// so MFMA B-frags are contiguous 16B/lane). We1T: [128][256] bf16.
// attn blocks: LDS-stage 84 x-rows, per-wave butterfly dots, write bandw and
// the bf16 copy of x (GEMM-1 / head A operand).
__global__ __launch_bounds__(256) void prep_kernel(
    const float* __restrict__ x,
    const float* __restrict__ p0, const float* __restrict__ p1,
    const float* __restrict__ p2, const float* __restrict__ p3,
    const float* __restrict__ p4,
    const float* __restrict__ q0, const float* __restrict__ q1,
    const float* __restrict__ q2, const float* __restrict__ q3,
    const float* __restrict__ q4,
    const float* __restrict__ we1,
    u16* __restrict__ W1T, u16* __restrict__ W2T, u16* __restrict__ We1T,
    u16* __restrict__ xb, float* __restrict__ bandw)
{
    __shared__ float Xs[84][128];
    const int tid = threadIdx.x;

    if (blockIdx.x < 64) {
        int t = blockIdx.x * 256 + tid;              // 0..16383
        const float* Ws1[5] = {p0, p1, p2, p3, p4};
        const float* Ws2[5] = {q0, q1, q2, q3, q4};
        #pragma unroll
        for (int r = 0; r < 5; ++r) {
            int idx = t + r * 16384;                 // 0..81919, r == n>>7
            int k = idx & 127, c = (idx >> 7) & 127;
            W1T[idx] = f2b(Ws1[r][k * 128 + c]);
            W2T[idx] = f2b(Ws2[r][k * 128 + c]);
        }
        #pragma unroll
        for (int r = 0; r < 2; ++r) {
            int idx = t + r * 16384;                 // 0..32767
            int n = idx >> 8, k = idx & 255;
            We1T[idx] = f2b(we1[k * 128 + n]);
        }
        return;
    }

    const int r0 = (blockIdx.x - 64) * 64;           // this block's row base
    // stage x[r0-10 .. r0+74) (clamped) into Xs
    for (int it = 0; it < 11; ++it) {
        int f = tid + it * 256;
        if (f < 84 * 32) {
            int s = f >> 5, c = f & 31;
            int g = r0 - WINW + s;
            if (g >= 0 && g < NN)
                *reinterpret_cast<float4*>(&Xs[s][c * 4]) =
                    *reinterpret_cast<const float4*>(&x[(size_t)g * DD + c * 4]);
        }
    }
    __syncthreads();

    // bf16 copy of this block's 64 rows (from LDS)
    for (int it = 0; it < 32; ++it) {
        int f = tid + it * 256;                      // 0..8191
        int row = f >> 7, col = f & 127;
        xb[(size_t)(r0 + row) * DD + col] = f2b(Xs[row + WINW][col]);
    }

    const int wave = tid >> 6, lane = tid & 63;
    for (int t = 0; t < 16; ++t) {
        int il = wave * 16 + t;                      // 0..63
        int i  = r0 + il;
        float xa = Xs[il + WINW][lane];
        float xbv = Xs[il + WINW][64 + lane];
        float m = 0.f, s_sel = -1e30f;               // m includes off-band zeros
        #pragma unroll
        for (int o = 0; o < 21; ++o) {
            int j = i - WINW + o;                    // wave-uniform guard
            float v = -1e30f;
            if (j >= 0 && j < NN) {
                float p = xa * Xs[il + o][lane] + xbv * Xs[il + o][64 + lane];
                #pragma unroll
                for (int off = 32; off; off >>= 1) p += __shfl_xor(p, off);
                v = p;
                m = fmaxf(m, v);
            }
            if (o == lane) s_sel = v;                // lane o keeps offset o
        }
        float ev = (s_sel > -1e29f) ? expf(s_sel - m) : 0.f;   // lanes>=21 -> 0
        int lo = i - WINW; if (lo < 0) lo = 0;
        int hi = i + WINW; if (hi > NN - 1) hi = NN - 1;
        float Z = ev;
        #pragma unroll
        for (int off = 32; off; off >>= 1) Z += __shfl_xor(Z, off);
        Z += (float)(NN - (hi - lo + 1)) * expf(-m);
        if (lane < 21) bandw[i * 32 + lane] = ev / Z;
    }
}

// ---------------- layer GEMM (MFMA): C[6144,640] = A_bf16[6144,128] @ B -----
// BT is [640][128] bf16 (pre-transposed). No LDS: A/B are L2-resident; frags
// gathered as 16B/lane dwordx4 (4 quads cover one 64B line -> no over-fetch).
// Block: 64(M) x 128(N), 4 waves in 2x2; wave: 32x64 via 2x4 16x16x32 frags.
__global__ __launch_bounds__(256) void gemm_mfma_kernel(
    const u16* __restrict__ A, const u16* __restrict__ BT, float* __restrict__ C)
{
    const int tid  = threadIdx.x;
    const int wave = tid >> 6, lane = tid & 63;
    const int lm = lane & 15, quad = lane >> 4;
    const int wm = wave >> 1, wn = wave & 1;
    const int bm = blockIdx.y * 64, bn = blockIdx.x * 128;

    const u16* Ab = A  + (size_t)(bm + wm * 32 + lm) * 128 + quad * 8;
    const u16* Bb = BT + (size_t)(bn + wn * 64 + lm) * 128 + quad * 8;

    bf16x8 afr[2][4];
    #pragma unroll
    for (int mt = 0; mt < 2; ++mt)
        #pragma unroll
        for (int s = 0; s < 4; ++s)
            afr[mt][s] = *reinterpret_cast<const bf16x8*>(Ab + mt * 16 * 128 + s * 32);

    f32x4 acc[2][4];
    #pragma unroll
    for (int mt = 0; mt < 2; ++mt)
        #pragma unroll
        for (int nt = 0; nt < 4; ++nt) acc[mt][nt] = {0.f, 0.f, 0.f, 0.f};

    #pragma unroll
    for (int s = 0; s < 4; ++s) {                    // K = 4 x 32
        bf16x8 bfr[4];
        #pragma unroll
        for (int nt = 0; nt < 4; ++nt)
            bfr[nt] = *reinterpret_cast<const bf16x8*>(Bb + nt * 16 * 128 + s * 32);
        #pragma unroll
        for (int mt = 0; mt < 2; ++mt)
            #pragma unroll
            for (int nt = 0; nt < 4; ++nt)
                acc[mt][nt] = __builtin_amdgcn_mfma_f32_16x16x32_bf16(
                    afr[mt][s], bfr[nt], acc[mt][nt], 0, 0, 0);
    }
    // C/D layout: col = lane&15, row = quad*4 + reg  [m89-verified]
    #pragma unroll
    for (int mt = 0; mt < 2; ++mt)
        #pragma unroll
        for (int nt = 0; nt < 4; ++nt)
            #pragma unroll
            for (int r = 0; r < 4; ++r) {
                int row = bm + wm * 32 + mt * 16 + quad * 4 + r;
                int col = bn + wn * 64 + nt * 16 + lm;
                C[(size_t)row * 640 + col] = acc[mt][nt][r];
            }
}

// ---------------- band combine: h = relu(sum_band w*Y[sel] + d*Y[aggr]) -----
__global__ __launch_bounds__(256) void combine_kernel(
    const float* __restrict__ Y, const float* __restrict__ bandw,
    const int* __restrict__ spk, u16* __restrict__ hb)
{
    int i = blockIdx.x * 2 + (threadIdx.x >> 7);
    int d = threadIdx.x & 127;
    int si = spk[i];
    float acc = bandw[i * 32 + WINW] * Y[(size_t)i * 640 + 512 + d];  // aggr*diag
    #pragma unroll
    for (int o = 0; o < 21; ++o) {
        int j = i - WINW + o;
        if (j < 0 || j >= NN) continue;
        float w = bandw[i * 32 + o];
        int sel = (spk[j] == si) ? ((j >= i) ? 0 : 1) : ((j >= i) ? 2 : 3);
        acc += w * Y[(size_t)j * 640 + sel * 128 + d];
    }
    hb[(size_t)i * 128 + d] = f2b(fmaxf(acc, 0.f));
}

// ---------------- head: E = relu([h2|x]@w_e1+b_e1) (MFMA) + fused tail ------
// Block: 64 rows, N=128 full, K=256 (h2b then xb). E-tile parked in LDS, then
// per-wave butterfly dots for the 7-wide emotion/sentiment heads.
__global__ __launch_bounds__(256) void head_kernel(
    const u16* __restrict__ h2b, const u16* __restrict__ xb,
    const u16* __restrict__ We1T, const float* __restrict__ be1,
    const float* __restrict__ we2, const float* __restrict__ be2,
    const float* __restrict__ ws,  const float* __restrict__ bs,
    float* __restrict__ out)
{
    __shared__ float Es[64][132];
    const int tid  = threadIdx.x;
    const int wave = tid >> 6, lane = tid & 63;
    const int lm = lane & 15, quad = lane >> 4;
    const int bm = blockIdx.x * 64;

    f32x4 acc[8];
    #pragma unroll
    for (int nt = 0; nt < 8; ++nt) acc[nt] = {0.f, 0.f, 0.f, 0.f};

    const u16* Ah = h2b + (size_t)(bm + wave * 16 + lm) * 128 + quad * 8;
    const u16* Ax = xb  + (size_t)(bm + wave * 16 + lm) * 128 + quad * 8;
    #pragma unroll
    for (int s = 0; s < 8; ++s) {                    // K = 8 x 32, h2 then x
        const u16* ap = (s < 4) ? (Ah + s * 32) : (Ax + (s - 4) * 32);
        bf16x8 a = *reinterpret_cast<const bf16x8*>(ap);
        #pragma unroll
        for (int nt = 0; nt < 8; ++nt) {
            // B-frag needs the SAME quad*8 k-offset as A (bug fixed here)
            bf16x8 b = *reinterpret_cast<const bf16x8*>(
                We1T + (size_t)(nt * 16 + lm) * 256 + s * 32 + quad * 8);
            acc[nt] = __builtin_amdgcn_mfma_f32_16x16x32_bf16(a, b, acc[nt], 0, 0, 0);
        }
    }
    #pragma unroll
    for (int nt = 0; nt < 8; ++nt) {
        int col = nt * 16 + lm;
        float bias = be1[col];
        #pragma unroll
        for (int r = 0; r < 4; ++r)
            Es[wave * 16 + quad * 4 + r][col] = fmaxf(acc[nt][r] + bias, 0.f);
    }
    __syncthreads();

    // tail: wave handles its own 16 rows
    float we2a[7], we2b[7], wsa[7], wsb[7], wsc[7], wsd[7];
    #pragma unroll
    for (int j = 0; j < 7; ++j) {
        we2a[j] = we2[lane * 7 + j];
        we2b[j] = we2[(lane + 64) * 7 + j];
        wsa[j]  = ws[lane * 7 + j];
        wsb[j]  = ws[(lane + 64) * 7 + j];
        wsc[j]  = ws[(lane + 128) * 7 + j];
        wsd[j]  = ws[(lane + 192) * 7 + j];
    }
    for (int t = 0; t < 16; ++t) {
        int rr = wave * 16 + t;
        int i  = bm + rr;
        float ea = Es[rr][lane], eb = Es[rr][64 + lane];
        float h0 = b2f(h2b[(size_t)i * 128 + lane]);
        float h1 = b2f(h2b[(size_t)i * 128 + 64 + lane]);
        float x0 = b2f(xb[(size_t)i * 128 + lane]);
        float x1 = b2f(xb[(size_t)i * 128 + 64 + lane]);
        #pragma unroll
        for (int j = 0; j < 7; ++j) {
            float p = ea * we2a[j] + eb * we2b[j];
            float q = h0 * wsa[j] + h1 * wsb[j] + x0 * wsc[j] + x1 * wsd[j];
            #pragma unroll
            for (int off = 32; off; off >>= 1) {
                p += __shfl_xor(p, off);
                q += __shfl_xor(q, off);
            }
            if (lane == 0) {
                out[i * 7 + j]          = p + be2[j];
                out[NN * 7 + i * 7 + j] = q + bs[j];
            }
        }
    }
}

extern "C" void kernel_launch(void* const* d_in, const int* in_sizes, int n_in,
                              void* d_out, int out_size, void* d_ws, size_t ws_size,
                              hipStream_t stream)
{
    const float* x   = (const float*)d_in[0];
    const int*   spk = (const int*)d_in[1];
    const float* Wp1 = (const float*)d_in[2];
    const float* Wu1 = (const float*)d_in[3];
    const float* Wm1 = (const float*)d_in[4];
    const float* Wd1 = (const float*)d_in[5];
    const float* Wp2 = (const float*)d_in[6];
    const float* Wu2 = (const float*)d_in[7];
    const float* Wm2 = (const float*)d_in[8];
    const float* Wd2 = (const float*)d_in[9];
    const float* wa1 = (const float*)d_in[10];
    const float* wa2 = (const float*)d_in[11];
    const float* we1 = (const float*)d_in[12];
    const float* be1 = (const float*)d_in[13];
    const float* we2 = (const float*)d_in[14];
    const float* be2 = (const float*)d_in[15];
    const float* wss = (const float*)d_in[16];
    const float* bss = (const float*)d_in[17];

    // workspace layout (bytes; all offsets 16B-aligned), total ~20.6 MB
    char* base = (char*)d_ws;
    float* bandw = (float*)(base);                 //  786,432 B
    float* Y     = (float*)(base + 786432);        // 15,728,640 B
    u16*   W1T   = (u16*)(base + 16515072);        //   163,840 B
    u16*   W2T   = (u16*)(base + 16678912);        //   163,840 B
    u16*   We1T  = (u16*)(base + 16842752);        //    65,536 B
    u16*   xb    = (u16*)(base + 16908288);        // 1,572,864 B
    u16*   h1b   = (u16*)(base + 18481152);        // 1,572,864 B
    u16*   h2b   = (u16*)(base + 20054016);        // 1,572,864 B

    prep_kernel<<<160, 256, 0, stream>>>(x, Wp1, Wu1, Wm1, Wd1, wa1,
                                         Wp2, Wu2, Wm2, Wd2, wa2, we1,
                                         W1T, W2T, We1T, xb, bandw);
    gemm_mfma_kernel<<<dim3(5, 96), 256, 0, stream>>>(xb, W1T, Y);
    combine_kernel<<<NN / 2, 256, 0, stream>>>(Y, bandw, spk, h1b);
    gemm_mfma_kernel<<<dim3(5, 96), 256, 0, stream>>>(h1b, W2T, Y);
    combine_kernel<<<NN / 2, 256, 0, stream>>>(Y, bandw, spk, h2b);
    head_kernel<<<96, 256, 0, stream>>>(h2b, xb, We1T, be1, we2, be2, wss, bss,
                                        (float*)d_out);
}

// Round 5
// 195.953 us; speedup vs baseline: 1.5542x; 1.5542x over previous
//
#include <hip/hip_runtime.h>
#include <hip/hip_bf16.h>

// DialogueGCN on MI355X — fp32 in/out; bf16 MFMA for all matmuls, fp32 for the
// banded softmax (precision-critical). Off-band attn entries are <= e^-64
// (row max >= ||x_i||^2 ~ chi^2_128) -> dropped; only the 21-wide band
// matters. Softmax Z still counts the (N-band) off-band zeros.
// R5: attention is thread-per-(i,o) dot (no cross-lane ops, 192 blocks);
// head tail done with MFMA (sentiment = 9th N-tile of the E-GEMM, emotion =
// one extra MFMA pass over the LDS E-tile). R4's 92us prep was 4% occupancy
// + unhidden shuffle chains.

#define NN   6144
#define DD   128
#define WINW 10

typedef unsigned short u16;
typedef __attribute__((ext_vector_type(8))) short bf16x8;  // MFMA A/B frag (4 VGPR)
typedef __attribute__((ext_vector_type(4))) float f32x4;   // MFMA C/D frag

__device__ __forceinline__ float b2f(u16 u) {
    return __uint_as_float(((unsigned int)u) << 16);
}
__device__ __forceinline__ u16 f2b(float f) {
    __hip_bfloat16 h = __float2bfloat16(f);   // RNE
    return *reinterpret_cast<u16*>(&h);
}
// 8 consecutive fp32 -> bf16x8 fragment (two 16B loads + 8 cvt)
__device__ __forceinline__ bf16x8 cvt8(const float* p) {
    float4 u = *reinterpret_cast<const float4*>(p);
    float4 v = *reinterpret_cast<const float4*>(p + 4);
    bf16x8 r;
    r[0] = (short)f2b(u.x); r[1] = (short)f2b(u.y);
    r[2] = (short)f2b(u.z); r[3] = (short)f2b(u.w);
    r[4] = (short)f2b(v.x); r[5] = (short)f2b(v.y);
    r[6] = (short)f2b(v.z); r[7] = (short)f2b(v.w);
    return r;
}

// ---------------- prep: blocks [0,64) pack bf16 B^T weights; [64,256) attn --
// W1T/W2T: [640][128] bf16 (B pre-transposed: frag = contiguous 16B/lane).
// We1T: [128][256]. we2T: [16][128], wsT: [16][256] (zero-padded cols 7..15).
// attn blocks: 32 rows each; thread-per-(i,o) fp32 dots from an LDS x-slab,
// then 32 threads finalize the banded softmax.
__global__ __launch_bounds__(256) void prep_kernel(
    const float* __restrict__ x,
    const float* __restrict__ p0, const float* __restrict__ p1,
    const float* __restrict__ p2, const float* __restrict__ p3,
    const float* __restrict__ p4,
    const float* __restrict__ q0, const float* __restrict__ q1,
    const float* __restrict__ q2, const float* __restrict__ q3,
    const float* __restrict__ q4,
    const float* __restrict__ we1, const float* __restrict__ we2,
    const float* __restrict__ ws,
    u16* __restrict__ W1T, u16* __restrict__ W2T, u16* __restrict__ We1T,
    u16* __restrict__ we2T, u16* __restrict__ wsT,
    float* __restrict__ bandw)
{
    const int tid = threadIdx.x;

    if (blockIdx.x < 64) {
        int t = blockIdx.x * 256 + tid;              // 0..16383
        const float* Ws1[5] = {p0, p1, p2, p3, p4};
        const float* Ws2[5] = {q0, q1, q2, q3, q4};
        #pragma unroll
        for (int r = 0; r < 5; ++r) {
            int idx = t + r * 16384;                 // 0..81919, r == n>>7
            int k = idx & 127, c = (idx >> 7) & 127;
            W1T[idx] = f2b(Ws1[r][k * 128 + c]);
            W2T[idx] = f2b(Ws2[r][k * 128 + c]);
        }
        #pragma unroll
        for (int r = 0; r < 2; ++r) {
            int idx = t + r * 16384;                 // 0..32767
            int n = idx >> 8, k = idx & 255;
            We1T[idx] = f2b(we1[k * 128 + n]);
        }
        if (blockIdx.x == 0) {
            #pragma unroll
            for (int r = 0; r < 8; ++r) {            // we2T: 16*128
                int idx = tid + r * 256;
                int n = idx >> 7, k = idx & 127;
                we2T[idx] = f2b(n < 7 ? we2[k * 7 + n] : 0.f);
            }
            #pragma unroll
            for (int r = 0; r < 16; ++r) {           // wsT: 16*256
                int idx = tid + r * 256;
                int n = idx >> 8, k = idx & 255;
                wsT[idx] = f2b(n < 7 ? ws[k * 7 + n] : 0.f);
            }
        }
        return;
    }

    __shared__ float Xs[52][132];                    // +4 pad: stride 4 banks
    __shared__ float Ss[32][24];
    const int r0 = (blockIdx.x - 64) * 32;           // 192 attn blocks

    // stage x[r0-10 .. r0+42) (clamped) into Xs
    #pragma unroll
    for (int it = 0; it < 7; ++it) {
        int f = tid + it * 256;
        if (f < 52 * 32) {
            int s = f >> 5, c = f & 31;
            int g = r0 - WINW + s;
            if (g >= 0 && g < NN)
                *reinterpret_cast<float4*>(&Xs[s][c * 4]) =
                    *reinterpret_cast<const float4*>(&x[(size_t)g * DD + c * 4]);
        }
    }
    __syncthreads();

    // thread-per-(row, offset) fp32 dot; 32*21 = 672 pairs
    #pragma unroll
    for (int r = 0; r < 3; ++r) {
        int p = tid + r * 256;
        if (p >= 672) break;
        int il = p / 21, o = p - il * 21;
        int jg = r0 + il - WINW + o;
        float sv = -1e30f;
        if (jg >= 0 && jg < NN) {
            const float* xr = &Xs[il + WINW][0];
            const float* jr = &Xs[il + o][0];
            float a0 = 0.f, a1 = 0.f, a2 = 0.f, a3 = 0.f;
            #pragma unroll 8
            for (int k4 = 0; k4 < 32; ++k4) {
                float4 a = *reinterpret_cast<const float4*>(xr + k4 * 4);
                float4 b = *reinterpret_cast<const float4*>(jr + k4 * 4);
                a0 = fmaf(a.x, b.x, a0); a1 = fmaf(a.y, b.y, a1);
                a2 = fmaf(a.z, b.z, a2); a3 = fmaf(a.w, b.w, a3);
            }
            sv = (a0 + a1) + (a2 + a3);
        }
        Ss[il][o] = sv;
    }
    __syncthreads();

    // finalize banded softmax: one thread per row
    if (tid < 32) {
        int il = tid, i = r0 + il;
        float m = 0.f;                               // off-band zeros count in max
        #pragma unroll
        for (int o = 0; o < 21; ++o) {
            float s = Ss[il][o];
            if (s > -1e29f) m = fmaxf(m, s);
        }
        int lo = i - WINW; if (lo < 0) lo = 0;
        int hi = i + WINW; if (hi > NN - 1) hi = NN - 1;
        float Z = (float)(NN - (hi - lo + 1)) * expf(-m);
        float ev[21];
        #pragma unroll
        for (int o = 0; o < 21; ++o) {
            float s = Ss[il][o];
            ev[o] = (s > -1e29f) ? expf(s - m) : 0.f;
            Z += ev[o];
        }
        #pragma unroll
        for (int o = 0; o < 21; ++o) bandw[i * 32 + o] = ev[o] / Z;
    }
}

// ---------------- layer GEMM (MFMA): C[6144,640] = A[6144,128] @ B ----------
// BT is [640][128] bf16. A either bf16 (Ab16) or fp32 (Af, converted in regs).
// No LDS: operands are L2-resident; frags are 16B/lane dwordx4 gathers.
// Block: 64(M) x 128(N), 4 waves in 2x2; wave: 32x64 via 2x4 16x16x32 frags.
__global__ __launch_bounds__(256) void gemm_mfma_kernel(
    const float* __restrict__ Af, const u16* __restrict__ Ab16,
    const u16* __restrict__ BT, float* __restrict__ C, int a_is_f32)
{
    const int tid  = threadIdx.x;
    const int wave = tid >> 6, lane = tid & 63;
    const int lm = lane & 15, quad = lane >> 4;
    const int wm = wave >> 1, wn = wave & 1;
    const int bm = blockIdx.y * 64, bn = blockIdx.x * 128;

    bf16x8 afr[2][4];
    if (a_is_f32) {
        #pragma unroll
        for (int mt = 0; mt < 2; ++mt)
            #pragma unroll
            for (int s = 0; s < 4; ++s)
                afr[mt][s] = cvt8(Af + (size_t)(bm + wm * 32 + mt * 16 + lm) * 128
                                      + s * 32 + quad * 8);
    } else {
        const u16* Ab = Ab16 + (size_t)(bm + wm * 32 + lm) * 128 + quad * 8;
        #pragma unroll
        for (int mt = 0; mt < 2; ++mt)
            #pragma unroll
            for (int s = 0; s < 4; ++s)
                afr[mt][s] = *reinterpret_cast<const bf16x8*>(Ab + mt * 16 * 128 + s * 32);
    }

    const u16* Bb = BT + (size_t)(bn + wn * 64 + lm) * 128 + quad * 8;
    f32x4 acc[2][4];
    #pragma unroll
    for (int mt = 0; mt < 2; ++mt)
        #pragma unroll
        for (int nt = 0; nt < 4; ++nt) acc[mt][nt] = {0.f, 0.f, 0.f, 0.f};

    #pragma unroll
    for (int s = 0; s < 4; ++s) {                    // K = 4 x 32
        bf16x8 bfr[4];
        #pragma unroll
        for (int nt = 0; nt < 4; ++nt)
            bfr[nt] = *reinterpret_cast<const bf16x8*>(Bb + nt * 16 * 128 + s * 32);
        #pragma unroll
        for (int mt = 0; mt < 2; ++mt)
            #pragma unroll
            for (int nt = 0; nt < 4; ++nt)
                acc[mt][nt] = __builtin_amdgcn_mfma_f32_16x16x32_bf16(
                    afr[mt][s], bfr[nt], acc[mt][nt], 0, 0, 0);
    }
    // C/D layout: col = lane&15, row = quad*4 + reg  [m89-verified]
    #pragma unroll
    for (int mt = 0; mt < 2; ++mt)
        #pragma unroll
        for (int nt = 0; nt < 4; ++nt)
            #pragma unroll
            for (int r = 0; r < 4; ++r) {
                int row = bm + wm * 32 + mt * 16 + quad * 4 + r;
                int col = bn + wn * 64 + nt * 16 + lm;
                C[(size_t)row * 640 + col] = acc[mt][nt][r];
            }
}

// ---------------- band combine: h = relu(sum_band w*Y[sel] + d*Y[aggr]) -----
__global__ __launch_bounds__(256) void combine_kernel(
    const float* __restrict__ Y, const float* __restrict__ bandw,
    const int* __restrict__ spk, u16* __restrict__ hb)
{
    int i = blockIdx.x * 2 + (threadIdx.x >> 7);
    int d = threadIdx.x & 127;
    int si = spk[i];
    float acc = bandw[i * 32 + WINW] * Y[(size_t)i * 640 + 512 + d];  // aggr*diag
    #pragma unroll
    for (int o = 0; o < 21; ++o) {
        int j = i - WINW + o;
        if (j < 0 || j >= NN) continue;
        float w = bandw[i * 32 + o];
        int sel = (spk[j] == si) ? ((j >= i) ? 0 : 1) : ((j >= i) ? 2 : 3);
        acc += w * Y[(size_t)j * 640 + sel * 128 + d];
    }
    hb[(size_t)i * 128 + d] = f2b(fmaxf(acc, 0.f));
}

// ---------------- head: E = relu([h2|x]@w_e1+b_e1); emo = E@we2; sent -------
// Block = 64 rows, 4 waves; wave w owns rows [w*16, w*16+16). One K=256 pass
// computes 8 E-tiles + the sentiment tile (ws as 9th, zero-padded N-tile).
// E parked in LDS (relu+bias), then one K=128 MFMA pass against we2T.
__global__ __launch_bounds__(256) void head_kernel(
    const u16* __restrict__ h2b, const float* __restrict__ x,
    const u16* __restrict__ We1T, const float* __restrict__ be1,
    const u16* __restrict__ we2T, const float* __restrict__ be2,
    const u16* __restrict__ wsT,  const float* __restrict__ bs,
    float* __restrict__ out)
{
    __shared__ float Es[64][132];
    const int tid  = threadIdx.x;
    const int wave = tid >> 6, lane = tid & 63;
    const int lm = lane & 15, quad = lane >> 4;
    const int bm = blockIdx.x * 64;
    const int row = bm + wave * 16 + lm;

    bf16x8 afr[8];                                   // K=256: h2 then x
    #pragma unroll
    for (int s = 0; s < 4; ++s)
        afr[s] = *reinterpret_cast<const bf16x8*>(
            &h2b[(size_t)row * 128 + s * 32 + quad * 8]);
    #pragma unroll
    for (int s = 4; s < 8; ++s)
        afr[s] = cvt8(&x[(size_t)row * 128 + (s - 4) * 32 + quad * 8]);

    f32x4 accE[8], accS = {0.f, 0.f, 0.f, 0.f};
    #pragma unroll
    for (int nt = 0; nt < 8; ++nt) accE[nt] = {0.f, 0.f, 0.f, 0.f};

    #pragma unroll
    for (int s = 0; s < 8; ++s) {
        #pragma unroll
        for (int nt = 0; nt < 8; ++nt) {
            bf16x8 b = *reinterpret_cast<const bf16x8*>(
                &We1T[(size_t)(nt * 16 + lm) * 256 + s * 32 + quad * 8]);
            accE[nt] = __builtin_amdgcn_mfma_f32_16x16x32_bf16(afr[s], b, accE[nt], 0, 0, 0);
        }
        bf16x8 bsf = *reinterpret_cast<const bf16x8*>(
            &wsT[(size_t)lm * 256 + s * 32 + quad * 8]);
        accS = __builtin_amdgcn_mfma_f32_16x16x32_bf16(afr[s], bsf, accS, 0, 0, 0);
    }

    // sentiment epilogue: col = lm (<7), row = quad*4 + r
    if (lm < 7) {
        #pragma unroll
        for (int r = 0; r < 4; ++r) {
            int i = bm + wave * 16 + quad * 4 + r;
            out[(size_t)NN * 7 + (size_t)i * 7 + lm] = accS[r] + bs[lm];
        }
    }
    // E tile -> LDS with bias+relu
    #pragma unroll
    for (int nt = 0; nt < 8; ++nt) {
        int col = nt * 16 + lm;
        float bias = be1[col];
        #pragma unroll
        for (int r = 0; r < 4; ++r)
            Es[wave * 16 + quad * 4 + r][col] = fmaxf(accE[nt][r] + bias, 0.f);
    }
    __syncthreads();

    // emotion: E[16 rows] @ we2 (K=128), A-frags from LDS (fp32 -> bf16)
    f32x4 accM = {0.f, 0.f, 0.f, 0.f};
    #pragma unroll
    for (int s = 0; s < 4; ++s) {
        bf16x8 a = cvt8(&Es[wave * 16 + lm][s * 32 + quad * 8]);
        bf16x8 b = *reinterpret_cast<const bf16x8*>(
            &we2T[(size_t)lm * 128 + s * 32 + quad * 8]);
        accM = __builtin_amdgcn_mfma_f32_16x16x32_bf16(a, b, accM, 0, 0, 0);
    }
    if (lm < 7) {
        #pragma unroll
        for (int r = 0; r < 4; ++r) {
            int i = bm + wave * 16 + quad * 4 + r;
            out[(size_t)i * 7 + lm] = accM[r] + be2[lm];
        }
    }
}

extern "C" void kernel_launch(void* const* d_in, const int* in_sizes, int n_in,
                              void* d_out, int out_size, void* d_ws, size_t ws_size,
                              hipStream_t stream)
{
    const float* x   = (const float*)d_in[0];
    const int*   spk = (const int*)d_in[1];
    const float* Wp1 = (const float*)d_in[2];
    const float* Wu1 = (const float*)d_in[3];
    const float* Wm1 = (const float*)d_in[4];
    const float* Wd1 = (const float*)d_in[5];
    const float* Wp2 = (const float*)d_in[6];
    const float* Wu2 = (const float*)d_in[7];
    const float* Wm2 = (const float*)d_in[8];
    const float* Wd2 = (const float*)d_in[9];
    const float* wa1 = (const float*)d_in[10];
    const float* wa2 = (const float*)d_in[11];
    const float* we1 = (const float*)d_in[12];
    const float* be1 = (const float*)d_in[13];
    const float* we2 = (const float*)d_in[14];
    const float* be2 = (const float*)d_in[15];
    const float* wss = (const float*)d_in[16];
    const float* bss = (const float*)d_in[17];

    // workspace layout (bytes; all offsets 16B-aligned), total ~20.1 MB
    char* base = (char*)d_ws;
    float* bandw = (float*)(base);                 //    786,432 B
    float* Y     = (float*)(base + 786432);        // 15,728,640 B
    u16*   W1T   = (u16*)(base + 16515072);        //    163,840 B
    u16*   W2T   = (u16*)(base + 16678912);        //    163,840 B
    u16*   We1T  = (u16*)(base + 16842752);        //     65,536 B
    u16*   we2T  = (u16*)(base + 16908288);        //      4,096 B
    u16*   wsT   = (u16*)(base + 16912384);        //      8,192 B
    u16*   h1b   = (u16*)(base + 16920576);        //  1,572,864 B
    u16*   h2b   = (u16*)(base + 18493440);        //  1,572,864 B

    prep_kernel<<<256, 256, 0, stream>>>(x, Wp1, Wu1, Wm1, Wd1, wa1,
                                         Wp2, Wu2, Wm2, Wd2, wa2,
                                         we1, we2, wss,
                                         W1T, W2T, We1T, we2T, wsT, bandw);
    gemm_mfma_kernel<<<dim3(5, 96), 256, 0, stream>>>(x, nullptr, W1T, Y, 1);
    combine_kernel<<<NN / 2, 256, 0, stream>>>(Y, bandw, spk, h1b);
    gemm_mfma_kernel<<<dim3(5, 96), 256, 0, stream>>>(nullptr, h1b, W2T, Y, 0);
    combine_kernel<<<NN / 2, 256, 0, stream>>>(Y, bandw, spk, h2b);
    head_kernel<<<96, 256, 0, stream>>>(h2b, x, We1T, be1, we2T, be2, wsT, bss,
                                        (float*)d_out);
}

// Round 6
// 181.479 us; speedup vs baseline: 1.6782x; 1.0798x over previous
//
#include <hip/hip_runtime.h>
#include <hip/hip_bf16.h>

// DialogueGCN on MI355X — fp32 in/out; bf16 MFMA everywhere, fp32 banded
// softmax. Off-band attn <= e^-64 -> dropped (row max >= ||x_i||^2 ~ 128);
// softmax Z still counts the (N-band) off-band zeros.
// R6: GEMM+band-combine fused per layer (Y tile lives in LDS as bf16, with
// +/-10-row halo computed redundantly; d-split lets each block need only 320
// of 640 N-cols). Head runs 384x64 (R5's 96-block head was latency-bound).
// Measured harness floor: ~170us of per-iteration reset overhead (268MB
// 0xAA ws poison fills at 43us dominate top-5); kernel sum is all we control.

#define NN   6144
#define DD   128
#define WINW 10

typedef unsigned short u16;
typedef __attribute__((ext_vector_type(8))) short bf16x8;  // MFMA A/B frag
typedef __attribute__((ext_vector_type(4))) float f32x4;   // MFMA C/D frag

__device__ __forceinline__ float b2f(u16 u) {
    return __uint_as_float(((unsigned int)u) << 16);
}
__device__ __forceinline__ u16 f2b(float f) {
    __hip_bfloat16 h = __float2bfloat16(f);   // RNE
    return *reinterpret_cast<u16*>(&h);
}
__device__ __forceinline__ bf16x8 cvt8(const float* p) {
    float4 u = *reinterpret_cast<const float4*>(p);
    float4 v = *reinterpret_cast<const float4*>(p + 4);
    bf16x8 r;
    r[0] = (short)f2b(u.x); r[1] = (short)f2b(u.y);
    r[2] = (short)f2b(u.z); r[3] = (short)f2b(u.w);
    r[4] = (short)f2b(v.x); r[5] = (short)f2b(v.y);
    r[6] = (short)f2b(v.z); r[7] = (short)f2b(v.w);
    return r;
}

// ---------------- prep: blocks [0,64) pack bf16 B^T weights; [64,256) attn --
__global__ __launch_bounds__(256) void prep_kernel(
    const float* __restrict__ x,
    const float* __restrict__ p0, const float* __restrict__ p1,
    const float* __restrict__ p2, const float* __restrict__ p3,
    const float* __restrict__ p4,
    const float* __restrict__ q0, const float* __restrict__ q1,
    const float* __restrict__ q2, const float* __restrict__ q3,
    const float* __restrict__ q4,
    const float* __restrict__ we1, const float* __restrict__ we2,
    const float* __restrict__ ws,
    u16* __restrict__ W1T, u16* __restrict__ W2T, u16* __restrict__ We1T,
    u16* __restrict__ we2T, u16* __restrict__ wsT,
    float* __restrict__ bandw)
{
    const int tid = threadIdx.x;

    if (blockIdx.x < 64) {
        int t = blockIdx.x * 256 + tid;              // 0..16383
        const float* Ws1[5] = {p0, p1, p2, p3, p4};
        const float* Ws2[5] = {q0, q1, q2, q3, q4};
        #pragma unroll
        for (int r = 0; r < 5; ++r) {
            int idx = t + r * 16384;                 // W*T[n][k] = W[k][n&127]
            int k = idx & 127, c = (idx >> 7) & 127;
            W1T[idx] = f2b(Ws1[r][k * 128 + c]);
            W2T[idx] = f2b(Ws2[r][k * 128 + c]);
        }
        #pragma unroll
        for (int r = 0; r < 2; ++r) {
            int idx = t + r * 16384;                 // We1T[n][k] (128x256)
            int n = idx >> 8, k = idx & 255;
            We1T[idx] = f2b(we1[k * 128 + n]);
        }
        if (blockIdx.x == 0) {
            #pragma unroll
            for (int r = 0; r < 8; ++r) {            // we2T: 16x128, pad n>=7
                int idx = tid + r * 256;
                int n = idx >> 7, k = idx & 127;
                we2T[idx] = f2b(n < 7 ? we2[k * 7 + n] : 0.f);
            }
            #pragma unroll
            for (int r = 0; r < 16; ++r) {           // wsT: 16x256, pad n>=7
                int idx = tid + r * 256;
                int n = idx >> 8, k = idx & 255;
                wsT[idx] = f2b(n < 7 ? ws[k * 7 + n] : 0.f);
            }
        }
        return;
    }

    __shared__ float Xs[52][132];
    __shared__ float Ss[32][24];
    const int r0 = (blockIdx.x - 64) * 32;           // 192 attn blocks

    #pragma unroll
    for (int it = 0; it < 7; ++it) {
        int f = tid + it * 256;
        if (f < 52 * 32) {
            int s = f >> 5, c = f & 31;
            int g = r0 - WINW + s;
            if (g >= 0 && g < NN)
                *reinterpret_cast<float4*>(&Xs[s][c * 4]) =
                    *reinterpret_cast<const float4*>(&x[(size_t)g * DD + c * 4]);
        }
    }
    __syncthreads();

    #pragma unroll
    for (int r = 0; r < 3; ++r) {                    // thread-per-(row,offset)
        int p = tid + r * 256;
        if (p >= 672) break;
        int il = p / 21, o = p - il * 21;
        int jg = r0 + il - WINW + o;
        float sv = -1e30f;
        if (jg >= 0 && jg < NN) {
            const float* xr = &Xs[il + WINW][0];
            const float* jr = &Xs[il + o][0];
            float a0 = 0.f, a1 = 0.f, a2 = 0.f, a3 = 0.f;
            #pragma unroll 8
            for (int k4 = 0; k4 < 32; ++k4) {
                float4 a = *reinterpret_cast<const float4*>(xr + k4 * 4);
                float4 b = *reinterpret_cast<const float4*>(jr + k4 * 4);
                a0 = fmaf(a.x, b.x, a0); a1 = fmaf(a.y, b.y, a1);
                a2 = fmaf(a.z, b.z, a2); a3 = fmaf(a.w, b.w, a3);
            }
            sv = (a0 + a1) + (a2 + a3);
        }
        Ss[il][o] = sv;
    }
    __syncthreads();

    if (tid < 32) {                                  // finalize softmax rows
        int il = tid, i = r0 + il;
        float m = 0.f;
        #pragma unroll
        for (int o = 0; o < 21; ++o) {
            float s = Ss[il][o];
            if (s > -1e29f) m = fmaxf(m, s);
        }
        int lo = i - WINW; if (lo < 0) lo = 0;
        int hi = i + WINW; if (hi > NN - 1) hi = NN - 1;
        float Z = (float)(NN - (hi - lo + 1)) * expf(-m);
        float ev[21];
        #pragma unroll
        for (int o = 0; o < 21; ++o) {
            float s = Ss[il][o];
            ev[o] = (s > -1e29f) ? expf(s - m) : 0.f;
            Z += ev[o];
        }
        #pragma unroll
        for (int o = 0; o < 21; ++o) bandw[i * 32 + o] = ev[o] / Z;
    }
}

// ---------------- fused layer: MFMA Y-tile (LDS) + band combine -------------
// Block (hb, by): rows [by*32, by*32+32) of h, cols [hb*64, hb*64+64).
// Computes Y rows [by*32-10, by*32+42) (pad to 64) x 320 cols
// ({sel*128 + hb*64 + [0,64)} for sel in 0..4) into LDS as bf16, then combines.
__global__ __launch_bounds__(256) void layer_kernel(
    const float* __restrict__ Af, const u16* __restrict__ Ab16,
    const u16* __restrict__ BT, const float* __restrict__ bandw,
    const int* __restrict__ spk, u16* __restrict__ hout, int a_is_f32)
{
    __shared__ u16 Ys[52][328];                      // stride 328 u16: <=4-way
    const int tid  = threadIdx.x;
    const int wave = tid >> 6, lane = tid & 63;
    const int lm = lane & 15, quad = lane >> 4;
    const int wm = wave >> 1, wn = wave & 1;         // 2x2 wave grid
    const int bm = blockIdx.y * 32;
    const int hb = blockIdx.x;

    bf16x8 afr[2][4];                                // 2 M-tiles x K=4x32
    #pragma unroll
    for (int mt = 0; mt < 2; ++mt) {
        int gr = bm - WINW + (wm * 2 + mt) * 16 + lm;
        gr = min(max(gr, 0), NN - 1);                // clamp halo (unused rows)
        #pragma unroll
        for (int s = 0; s < 4; ++s) {
            if (a_is_f32)
                afr[mt][s] = cvt8(Af + (size_t)gr * DD + s * 32 + quad * 8);
            else
                afr[mt][s] = *reinterpret_cast<const bf16x8*>(
                    Ab16 + (size_t)gr * DD + s * 32 + quad * 8);
        }
    }

    f32x4 acc[2][10];
    #pragma unroll
    for (int mt = 0; mt < 2; ++mt)
        #pragma unroll
        for (int n = 0; n < 10; ++n) acc[mt][n] = {0.f, 0.f, 0.f, 0.f};

    #pragma unroll
    for (int np = 0; np < 10; ++np) {
        int nt = wn * 10 + np;                       // 20 N-tiles of 16
        int gn = (nt >> 2) * 128 + hb * 64 + (nt & 3) * 16 + lm;
        #pragma unroll
        for (int s = 0; s < 4; ++s) {
            bf16x8 b = *reinterpret_cast<const bf16x8*>(
                BT + (size_t)gn * DD + s * 32 + quad * 8);
            acc[0][np] = __builtin_amdgcn_mfma_f32_16x16x32_bf16(afr[0][s], b, acc[0][np], 0, 0, 0);
            acc[1][np] = __builtin_amdgcn_mfma_f32_16x16x32_bf16(afr[1][s], b, acc[1][np], 0, 0, 0);
        }
    }
    // C/D: col = lane&15, row = quad*4 + reg — park bf16 tile in LDS
    #pragma unroll
    for (int mt = 0; mt < 2; ++mt)
        #pragma unroll
        for (int np = 0; np < 10; ++np) {
            int nt = wn * 10 + np;
            #pragma unroll
            for (int r = 0; r < 4; ++r) {
                int lr = (wm * 2 + mt) * 16 + quad * 4 + r;
                if (lr < 52) Ys[lr][nt * 16 + lm] = f2b(acc[mt][np][r]);
            }
        }
    __syncthreads();

    // band combine: d = lane (col within half), 8 rows per thread-group
    const int d = tid & 63, rg = tid >> 6;
    #pragma unroll
    for (int rr = 0; rr < 8; ++rr) {
        int il = rg * 8 + rr;
        int i  = bm + il;
        int si = spk[i];
        const float* bw = bandw + (size_t)i * 32;
        float a2 = bw[WINW] * b2f(Ys[il + WINW][256 + d]);   // aggr (sel 4)*diag
        #pragma unroll
        for (int o = 0; o < 21; ++o) {
            int j = i - WINW + o;
            if (j < 0 || j >= NN) continue;
            int sel = (spk[j] == si) ? ((j >= i) ? 0 : 1) : ((j >= i) ? 2 : 3);
            a2 += bw[o] * b2f(Ys[il + o][sel * 64 + d]);
        }
        hout[(size_t)i * DD + hb * 64 + d] = f2b(fmaxf(a2, 0.f));
    }
}

// ---------------- head: E = relu([h2|x]@w_e1+b_e1); emo = E@we2; sentiment --
// 384 blocks x 64 threads; one wave owns 16 rows. Sentiment = zero-padded
// 9th N-tile of the E-GEMM; emotion = K=128 MFMA pass over the LDS E-tile.
__global__ __launch_bounds__(64) void head_kernel(
    const u16* __restrict__ h2b, const float* __restrict__ x,
    const u16* __restrict__ We1T, const float* __restrict__ be1,
    const u16* __restrict__ we2T, const float* __restrict__ be2,
    const u16* __restrict__ wsT,  const float* __restrict__ bs,
    float* __restrict__ out)
{
    __shared__ float Es[16][132];
    const int lane = threadIdx.x;
    const int lm = lane & 15, quad = lane >> 4;
    const int bm = blockIdx.x * 16;
    const int row = bm + lm;

    bf16x8 afr[8];                                   // K=256: h2 then x
    #pragma unroll
    for (int s = 0; s < 4; ++s)
        afr[s] = *reinterpret_cast<const bf16x8*>(
            &h2b[(size_t)row * DD + s * 32 + quad * 8]);
    #pragma unroll
    for (int s = 4; s < 8; ++s)
        afr[s] = cvt8(&x[(size_t)row * DD + (s - 4) * 32 + quad * 8]);

    f32x4 accE[8], accS = {0.f, 0.f, 0.f, 0.f};
    #pragma unroll
    for (int nt = 0; nt < 8; ++nt) accE[nt] = {0.f, 0.f, 0.f, 0.f};

    #pragma unroll
    for (int s = 0; s < 8; ++s) {
        #pragma unroll
        for (int nt = 0; nt < 8; ++nt) {
            bf16x8 b = *reinterpret_cast<const bf16x8*>(
                &We1T[(size_t)(nt * 16 + lm) * 256 + s * 32 + quad * 8]);
            accE[nt] = __builtin_amdgcn_mfma_f32_16x16x32_bf16(afr[s], b, accE[nt], 0, 0, 0);
        }
        bf16x8 bsf = *reinterpret_cast<const bf16x8*>(
            &wsT[(size_t)lm * 256 + s * 32 + quad * 8]);
        accS = __builtin_amdgcn_mfma_f32_16x16x32_bf16(afr[s], bsf, accS, 0, 0, 0);
    }

    if (lm < 7) {                                    // sentiment epilogue
        #pragma unroll
        for (int r = 0; r < 4; ++r) {
            int i = bm + quad * 4 + r;
            out[(size_t)NN * 7 + (size_t)i * 7 + lm] = accS[r] + bs[lm];
        }
    }
    #pragma unroll
    for (int nt = 0; nt < 8; ++nt) {                 // E tile -> LDS (bias+relu)
        int col = nt * 16 + lm;
        float bias = be1[col];
        #pragma unroll
        for (int r = 0; r < 4; ++r)
            Es[quad * 4 + r][col] = fmaxf(accE[nt][r] + bias, 0.f);
    }
    __syncthreads();

    f32x4 accM = {0.f, 0.f, 0.f, 0.f};               // emotion: E @ we2
    #pragma unroll
    for (int s = 0; s < 4; ++s) {
        bf16x8 a = cvt8(&Es[lm][s * 32 + quad * 8]);
        bf16x8 b = *reinterpret_cast<const bf16x8*>(
            &we2T[(size_t)lm * 128 + s * 32 + quad * 8]);
        accM = __builtin_amdgcn_mfma_f32_16x16x32_bf16(a, b, accM, 0, 0, 0);
    }
    if (lm < 7) {
        #pragma unroll
        for (int r = 0; r < 4; ++r) {
            int i = bm + quad * 4 + r;
            out[(size_t)i * 7 + lm] = accM[r] + be2[lm];
        }
    }
}

extern "C" void kernel_launch(void* const* d_in, const int* in_sizes, int n_in,
                              void* d_out, int out_size, void* d_ws, size_t ws_size,
                              hipStream_t stream)
{
    const float* x   = (const float*)d_in[0];
    const int*   spk = (const int*)d_in[1];
    const float* Wp1 = (const float*)d_in[2];
    const float* Wu1 = (const float*)d_in[3];
    const float* Wm1 = (const float*)d_in[4];
    const float* Wd1 = (const float*)d_in[5];
    const float* Wp2 = (const float*)d_in[6];
    const float* Wu2 = (const float*)d_in[7];
    const float* Wm2 = (const float*)d_in[8];
    const float* Wd2 = (const float*)d_in[9];
    const float* wa1 = (const float*)d_in[10];
    const float* wa2 = (const float*)d_in[11];
    const float* we1 = (const float*)d_in[12];
    const float* be1 = (const float*)d_in[13];
    const float* we2 = (const float*)d_in[14];
    const float* be2 = (const float*)d_in[15];
    const float* wss = (const float*)d_in[16];
    const float* bss = (const float*)d_in[17];

    // workspace layout (bytes; 16B-aligned), total ~4.3 MB (no Y buffer)
    char* base = (char*)d_ws;
    float* bandw = (float*)(base);                 //   786,432 B
    u16*   W1T   = (u16*)(base + 786432);          //   163,840 B
    u16*   W2T   = (u16*)(base + 950272);          //   163,840 B
    u16*   We1T  = (u16*)(base + 1114112);         //    65,536 B
    u16*   we2T  = (u16*)(base + 1179648);         //     4,096 B
    u16*   wsT   = (u16*)(base + 1183744);         //     8,192 B
    u16*   h1b   = (u16*)(base + 1191936);         // 1,572,864 B
    u16*   h2b   = (u16*)(base + 2764800);         // 1,572,864 B

    prep_kernel<<<256, 256, 0, stream>>>(x, Wp1, Wu1, Wm1, Wd1, wa1,
                                         Wp2, Wu2, Wm2, Wd2, wa2,
                                         we1, we2, wss,
                                         W1T, W2T, We1T, we2T, wsT, bandw);
    layer_kernel<<<dim3(2, 192), 256, 0, stream>>>(x, nullptr, W1T, bandw, spk, h1b, 1);
    layer_kernel<<<dim3(2, 192), 256, 0, stream>>>(nullptr, h1b, W2T, bandw, spk, h2b, 0);
    head_kernel<<<384, 64, 0, stream>>>(h2b, x, We1T, be1, we2T, be2, wsT, bss,
                                        (float*)d_out);
}

// Round 7
// 138.981 us; speedup vs baseline: 2.1913x; 1.3058x over previous
//
#include <hip/hip_runtime.h>
#include <hip/hip_bf16.h>

// DialogueGCN on MI355X — fp32 in/out; bf16 MFMA everywhere, fp32 banded
// softmax. Off-band attn <= e^-64 -> dropped (row max >= ||x_i||^2 ~ 128);
// softmax Z still counts the (N-band) off-band zeros.
// R7: layer kernel de-latency-fied. R6 measured 54us with ALL pipes idle
// (MfmaUtil 1.2, VALU 8.8, HBM 2%, Occ 16%): 1.5 blocks/CU + a serial
// spk->sel->LDS->fma chain per combine iteration. Fix: (a) pre-resolved
// (w, offset) int2 tables in LDS built once per block (combine inner loop =
// ds_read_b64 + ds_read_b32 + 2 fma, zero global traffic, zero branches);
// (b) 32-col blocks -> grid (4,192) = 768 blocks = 3 blocks/CU.

#define NN   6144
#define DD   128
#define WINW 10
#define YST  168   // Ys row stride (u16): 160 cols + 8 pad

typedef unsigned short u16;
typedef __attribute__((ext_vector_type(8))) short bf16x8;  // MFMA A/B frag
typedef __attribute__((ext_vector_type(4))) float f32x4;   // MFMA C/D frag

__device__ __forceinline__ float b2f(u16 u) {
    return __uint_as_float(((unsigned int)u) << 16);
}
__device__ __forceinline__ u16 f2b(float f) {
    __hip_bfloat16 h = __float2bfloat16(f);   // RNE
    return *reinterpret_cast<u16*>(&h);
}
__device__ __forceinline__ bf16x8 cvt8(const float* p) {
    float4 u = *reinterpret_cast<const float4*>(p);
    float4 v = *reinterpret_cast<const float4*>(p + 4);
    bf16x8 r;
    r[0] = (short)f2b(u.x); r[1] = (short)f2b(u.y);
    r[2] = (short)f2b(u.z); r[3] = (short)f2b(u.w);
    r[4] = (short)f2b(v.x); r[5] = (short)f2b(v.y);
    r[6] = (short)f2b(v.z); r[7] = (short)f2b(v.w);
    return r;
}

// ---------------- prep: blocks [0,64) pack bf16 B^T weights; [64,256) attn --
__global__ __launch_bounds__(256) void prep_kernel(
    const float* __restrict__ x,
    const float* __restrict__ p0, const float* __restrict__ p1,
    const float* __restrict__ p2, const float* __restrict__ p3,
    const float* __restrict__ p4,
    const float* __restrict__ q0, const float* __restrict__ q1,
    const float* __restrict__ q2, const float* __restrict__ q3,
    const float* __restrict__ q4,
    const float* __restrict__ we1, const float* __restrict__ we2,
    const float* __restrict__ ws,
    u16* __restrict__ W1T, u16* __restrict__ W2T, u16* __restrict__ We1T,
    u16* __restrict__ we2T, u16* __restrict__ wsT,
    float* __restrict__ bandw)
{
    const int tid = threadIdx.x;

    if (blockIdx.x < 64) {
        int t = blockIdx.x * 256 + tid;              // 0..16383
        const float* Ws1[5] = {p0, p1, p2, p3, p4};
        const float* Ws2[5] = {q0, q1, q2, q3, q4};
        #pragma unroll
        for (int r = 0; r < 5; ++r) {
            int idx = t + r * 16384;                 // W*T[n][k] = W[k][n&127]
            int k = idx & 127, c = (idx >> 7) & 127;
            W1T[idx] = f2b(Ws1[r][k * 128 + c]);
            W2T[idx] = f2b(Ws2[r][k * 128 + c]);
        }
        #pragma unroll
        for (int r = 0; r < 2; ++r) {
            int idx = t + r * 16384;                 // We1T[n][k] (128x256)
            int n = idx >> 8, k = idx & 255;
            We1T[idx] = f2b(we1[k * 128 + n]);
        }
        if (blockIdx.x == 0) {
            #pragma unroll
            for (int r = 0; r < 8; ++r) {            // we2T: 16x128, pad n>=7
                int idx = tid + r * 256;
                int n = idx >> 7, k = idx & 127;
                we2T[idx] = f2b(n < 7 ? we2[k * 7 + n] : 0.f);
            }
            #pragma unroll
            for (int r = 0; r < 16; ++r) {           // wsT: 16x256, pad n>=7
                int idx = tid + r * 256;
                int n = idx >> 8, k = idx & 255;
                wsT[idx] = f2b(n < 7 ? ws[k * 7 + n] : 0.f);
            }
        }
        return;
    }

    __shared__ float Xs[52][132];
    __shared__ float Ss[32][24];
    const int r0 = (blockIdx.x - 64) * 32;           // 192 attn blocks

    #pragma unroll
    for (int it = 0; it < 7; ++it) {
        int f = tid + it * 256;
        if (f < 52 * 32) {
            int s = f >> 5, c = f & 31;
            int g = r0 - WINW + s;
            if (g >= 0 && g < NN)
                *reinterpret_cast<float4*>(&Xs[s][c * 4]) =
                    *reinterpret_cast<const float4*>(&x[(size_t)g * DD + c * 4]);
        }
    }
    __syncthreads();

    #pragma unroll
    for (int r = 0; r < 3; ++r) {                    // thread-per-(row,offset)
        int p = tid + r * 256;
        if (p >= 672) break;
        int il = p / 21, o = p - il * 21;
        int jg = r0 + il - WINW + o;
        float sv = -1e30f;
        if (jg >= 0 && jg < NN) {
            const float* xr = &Xs[il + WINW][0];
            const float* jr = &Xs[il + o][0];
            float a0 = 0.f, a1 = 0.f, a2 = 0.f, a3 = 0.f;
            #pragma unroll 8
            for (int k4 = 0; k4 < 32; ++k4) {
                float4 a = *reinterpret_cast<const float4*>(xr + k4 * 4);
                float4 b = *reinterpret_cast<const float4*>(jr + k4 * 4);
                a0 = fmaf(a.x, b.x, a0); a1 = fmaf(a.y, b.y, a1);
                a2 = fmaf(a.z, b.z, a2); a3 = fmaf(a.w, b.w, a3);
            }
            sv = (a0 + a1) + (a2 + a3);
        }
        Ss[il][o] = sv;
    }
    __syncthreads();

    if (tid < 32) {                                  // finalize softmax rows
        int il = tid, i = r0 + il;
        float m = 0.f;
        #pragma unroll
        for (int o = 0; o < 21; ++o) {
            float s = Ss[il][o];
            if (s > -1e29f) m = fmaxf(m, s);
        }
        int lo = i - WINW; if (lo < 0) lo = 0;
        int hi = i + WINW; if (hi > NN - 1) hi = NN - 1;
        float Z = (float)(NN - (hi - lo + 1)) * expf(-m);
        float ev[21];
        #pragma unroll
        for (int o = 0; o < 21; ++o) {
            float s = Ss[il][o];
            ev[o] = (s > -1e29f) ? expf(s - m) : 0.f;
            Z += ev[o];
        }
        #pragma unroll
        for (int o = 0; o < 21; ++o) bandw[i * 32 + o] = ev[o] / Z;
    }
}

// ---------------- fused layer: MFMA Y-tile (LDS) + table-driven combine -----
// Block (hb, by): rows [by*32, by*32+32) of h, cols [hb*32, hb*32+32).
// Phase 0: build 32x22 (w, Ys-offset) pairs in LDS (all global reads here).
// Phase 1: Y rows [by*32-10, by*32+42) (pad 64) x {sel*128+hb*32+[0,32)} for
// sel 0..4 -> bf16 LDS tile. Phase 2: combine = pure LDS reads + fma.
__global__ __launch_bounds__(256) void layer_kernel(
    const float* __restrict__ Af, const u16* __restrict__ Ab16,
    const u16* __restrict__ BT, const float* __restrict__ bandw,
    const int* __restrict__ spk, u16* __restrict__ hout, int a_is_f32)
{
    __shared__ u16 Ys[52][YST];
    __shared__ int2 tab[32 * 22];                    // {w bits, u16 offset}
    const int tid  = threadIdx.x;
    const int wave = tid >> 6, lane = tid & 63;
    const int lm = lane & 15, quad = lane >> 4;
    const int wm = wave >> 1, wn = wave & 1;         // 2x2 wave grid
    const int bm = blockIdx.y * 32;
    const int hb = blockIdx.x;                       // 0..3, 32-col slice

    // Phase 0: pre-resolve combine coefficients/offsets (overlaps phase 1)
    for (int p = tid; p < 704; p += 256) {
        int il = p / 22, e = p - il * 22;
        int i  = bm + il;
        int si = spk[i];
        float w; int off;
        if (e < 21) {
            int j = i - WINW + e;
            bool valid = (j >= 0) && (j < NN);
            int jc  = valid ? j : i;
            int sel = (spk[jc] == si) ? ((j >= i) ? 0 : 1) : ((j >= i) ? 2 : 3);
            w   = valid ? bandw[(size_t)i * 32 + e] : 0.f;
            off = valid ? (il + e) * YST + sel * 32 : 0;   // Ys[0][0] is written
        } else {                                     // aggr * diag term
            w   = bandw[(size_t)i * 32 + WINW];
            off = (il + WINW) * YST + 4 * 32;
        }
        tab[p] = make_int2(__float_as_int(w), off);
    }

    // Phase 1: MFMA the 64(M incl halo+pad) x 160(N) Y-tile into LDS
    bf16x8 afr[2][4];
    #pragma unroll
    for (int mt = 0; mt < 2; ++mt) {
        int gr = bm - WINW + (wm * 2 + mt) * 16 + lm;
        gr = min(max(gr, 0), NN - 1);                // clamp halo/pad rows
        #pragma unroll
        for (int s = 0; s < 4; ++s) {
            if (a_is_f32)
                afr[mt][s] = cvt8(Af + (size_t)gr * DD + s * 32 + quad * 8);
            else
                afr[mt][s] = *reinterpret_cast<const bf16x8*>(
                    Ab16 + (size_t)gr * DD + s * 32 + quad * 8);
        }
    }

    f32x4 acc[2][5];
    #pragma unroll
    for (int mt = 0; mt < 2; ++mt)
        #pragma unroll
        for (int n = 0; n < 5; ++n) acc[mt][n] = {0.f, 0.f, 0.f, 0.f};

    #pragma unroll
    for (int np = 0; np < 5; ++np) {
        int nt = wn * 5 + np;                        // 10 N-tiles of 16
        int gn = (nt >> 1) * 128 + hb * 32 + (nt & 1) * 16 + lm;
        #pragma unroll
        for (int s = 0; s < 4; ++s) {
            bf16x8 b = *reinterpret_cast<const bf16x8*>(
                BT + (size_t)gn * DD + s * 32 + quad * 8);
            acc[0][np] = __builtin_amdgcn_mfma_f32_16x16x32_bf16(afr[0][s], b, acc[0][np], 0, 0, 0);
            acc[1][np] = __builtin_amdgcn_mfma_f32_16x16x32_bf16(afr[1][s], b, acc[1][np], 0, 0, 0);
        }
    }
    // C/D: col = lane&15, row = quad*4 + reg
    #pragma unroll
    for (int mt = 0; mt < 2; ++mt)
        #pragma unroll
        for (int np = 0; np < 5; ++np) {
            int nt = wn * 5 + np;
            #pragma unroll
            for (int r = 0; r < 4; ++r) {
                int lr = (wm * 2 + mt) * 16 + quad * 4 + r;
                if (lr < 52) Ys[lr][nt * 16 + lm] = f2b(acc[mt][np][r]);
            }
        }
    __syncthreads();

    // Phase 2: combine — 16 row-groups x (16 threads x 2 cols), LDS-only
    const int c0 = (tid & 15) * 2;
    const int rg = tid >> 4;
    #pragma unroll
    for (int rr = 0; rr < 2; ++rr) {
        int il = rg * 2 + rr;
        float a0 = 0.f, a1 = 0.f;
        const int2* tp = &tab[il * 22];
        #pragma unroll
        for (int e = 0; e < 22; ++e) {
            int2 t = tp[e];
            float w = __int_as_float(t.x);
            unsigned y2 = *reinterpret_cast<const unsigned*>(
                &Ys[0][0] + t.y + c0);
            a0 = fmaf(w, b2f((u16)(y2 & 0xffff)), a0);
            a1 = fmaf(w, b2f((u16)(y2 >> 16)), a1);
        }
        int i = bm + il;
        unsigned pk = ((unsigned)f2b(fmaxf(a1, 0.f)) << 16) | f2b(fmaxf(a0, 0.f));
        *reinterpret_cast<unsigned*>(&hout[(size_t)i * DD + hb * 32 + c0]) = pk;
    }
}

// ---------------- head: E = relu([h2|x]@w_e1+b_e1); emo = E@we2; sentiment --
__global__ __launch_bounds__(64) void head_kernel(
    const u16* __restrict__ h2b, const float* __restrict__ x,
    const u16* __restrict__ We1T, const float* __restrict__ be1,
    const u16* __restrict__ we2T, const float* __restrict__ be2,
    const u16* __restrict__ wsT,  const float* __restrict__ bs,
    float* __restrict__ out)
{
    __shared__ float Es[16][132];
    const int lane = threadIdx.x;
    const int lm = lane & 15, quad = lane >> 4;
    const int bm = blockIdx.x * 16;
    const int row = bm + lm;

    bf16x8 afr[8];                                   // K=256: h2 then x
    #pragma unroll
    for (int s = 0; s < 4; ++s)
        afr[s] = *reinterpret_cast<const bf16x8*>(
            &h2b[(size_t)row * DD + s * 32 + quad * 8]);
    #pragma unroll
    for (int s = 4; s < 8; ++s)
        afr[s] = cvt8(&x[(size_t)row * DD + (s - 4) * 32 + quad * 8]);

    f32x4 accE[8], accS = {0.f, 0.f, 0.f, 0.f};
    #pragma unroll
    for (int nt = 0; nt < 8; ++nt) accE[nt] = {0.f, 0.f, 0.f, 0.f};

    #pragma unroll
    for (int s = 0; s < 8; ++s) {
        #pragma unroll
        for (int nt = 0; nt < 8; ++nt) {
            bf16x8 b = *reinterpret_cast<const bf16x8*>(
                &We1T[(size_t)(nt * 16 + lm) * 256 + s * 32 + quad * 8]);
            accE[nt] = __builtin_amdgcn_mfma_f32_16x16x32_bf16(afr[s], b, accE[nt], 0, 0, 0);
        }
        bf16x8 bsf = *reinterpret_cast<const bf16x8*>(
            &wsT[(size_t)lm * 256 + s * 32 + quad * 8]);
        accS = __builtin_amdgcn_mfma_f32_16x16x32_bf16(afr[s], bsf, accS, 0, 0, 0);
    }

    if (lm < 7) {                                    // sentiment epilogue
        #pragma unroll
        for (int r = 0; r < 4; ++r) {
            int i = bm + quad * 4 + r;
            out[(size_t)NN * 7 + (size_t)i * 7 + lm] = accS[r] + bs[lm];
        }
    }
    #pragma unroll
    for (int nt = 0; nt < 8; ++nt) {                 // E tile -> LDS (bias+relu)
        int col = nt * 16 + lm;
        float bias = be1[col];
        #pragma unroll
        for (int r = 0; r < 4; ++r)
            Es[quad * 4 + r][col] = fmaxf(accE[nt][r] + bias, 0.f);
    }
    __syncthreads();

    f32x4 accM = {0.f, 0.f, 0.f, 0.f};               // emotion: E @ we2
    #pragma unroll
    for (int s = 0; s < 4; ++s) {
        bf16x8 a = cvt8(&Es[lm][s * 32 + quad * 8]);
        bf16x8 b = *reinterpret_cast<const bf16x8*>(
            &we2T[(size_t)lm * 128 + s * 32 + quad * 8]);
        accM = __builtin_amdgcn_mfma_f32_16x16x32_bf16(a, b, accM, 0, 0, 0);
    }
    if (lm < 7) {
        #pragma unroll
        for (int r = 0; r < 4; ++r) {
            int i = bm + quad * 4 + r;
            out[(size_t)i * 7 + lm] = accM[r] + be2[lm];
        }
    }
}

extern "C" void kernel_launch(void* const* d_in, const int* in_sizes, int n_in,
                              void* d_out, int out_size, void* d_ws, size_t ws_size,
                              hipStream_t stream)
{
    const float* x   = (const float*)d_in[0];
    const int*   spk = (const int*)d_in[1];
    const float* Wp1 = (const float*)d_in[2];
    const float* Wu1 = (const float*)d_in[3];
    const float* Wm1 = (const float*)d_in[4];
    const float* Wd1 = (const float*)d_in[5];
    const float* Wp2 = (const float*)d_in[6];
    const float* Wu2 = (const float*)d_in[7];
    const float* Wm2 = (const float*)d_in[8];
    const float* Wd2 = (const float*)d_in[9];
    const float* wa1 = (const float*)d_in[10];
    const float* wa2 = (const float*)d_in[11];
    const float* we1 = (const float*)d_in[12];
    const float* be1 = (const float*)d_in[13];
    const float* we2 = (const float*)d_in[14];
    const float* be2 = (const float*)d_in[15];
    const float* wss = (const float*)d_in[16];
    const float* bss = (const float*)d_in[17];

    // workspace layout (bytes; 16B-aligned), total ~4.3 MB
    char* base = (char*)d_ws;
    float* bandw = (float*)(base);                 //   786,432 B
    u16*   W1T   = (u16*)(base + 786432);          //   163,840 B
    u16*   W2T   = (u16*)(base + 950272);          //   163,840 B
    u16*   We1T  = (u16*)(base + 1114112);         //    65,536 B
    u16*   we2T  = (u16*)(base + 1179648);         //     4,096 B
    u16*   wsT   = (u16*)(base + 1183744);         //     8,192 B
    u16*   h1b   = (u16*)(base + 1191936);         // 1,572,864 B
    u16*   h2b   = (u16*)(base + 2764800);         // 1,572,864 B

    prep_kernel<<<256, 256, 0, stream>>>(x, Wp1, Wu1, Wm1, Wd1, wa1,
                                         Wp2, Wu2, Wm2, Wd2, wa2,
                                         we1, we2, wss,
                                         W1T, W2T, We1T, we2T, wsT, bandw);
    layer_kernel<<<dim3(4, 192), 256, 0, stream>>>(x, nullptr, W1T, bandw, spk, h1b, 1);
    layer_kernel<<<dim3(4, 192), 256, 0, stream>>>(nullptr, h1b, W2T, bandw, spk, h2b, 0);
    head_kernel<<<384, 64, 0, stream>>>(h2b, x, We1T, be1, we2T, be2, wsT, bss,
                                        (float*)d_out);
}